// Round 17
// baseline (233.882 us; speedup 1.0000x reference)
//
#include <hip/hip_runtime.h>

#define SEQ   2048
#define BATCH 2
#define HID   2048
#define NHEAD 16
#define HDIM  128
#define MTOT  4096
#define KDIM  2048

typedef __attribute__((ext_vector_type(8))) short  bf16x8;
typedef __attribute__((ext_vector_type(4))) float  f32x4;
typedef __attribute__((ext_vector_type(4))) unsigned short u16x4;
typedef __attribute__((ext_vector_type(8))) unsigned short u16x8;

__device__ __forceinline__ unsigned short f2bf(float x) {
  unsigned u = __float_as_uint(x);
  u += 0x7fffu + ((u >> 16) & 1u);
  return (unsigned short)(u >> 16);
}

__device__ __forceinline__ float fexp2(float x) {
  float r;
  asm("v_exp_f32 %0, %1" : "=v"(r) : "v"(x));
  return r;
}

__device__ __forceinline__ void gl_lds16(const void* g, void* l) {
  __builtin_amdgcn_global_load_lds(
      (__attribute__((address_space(1))) void*)g,
      (__attribute__((address_space(3))) void*)l, 16, 0, 0);
}

__device__ __forceinline__ f32x4 mfma16(bf16x8 a, bf16x8 b, f32x4 c) {
  return __builtin_amdgcn_mfma_f32_16x16x32_bf16(a, b, c, 0, 0, 0);
}

// ---------------------------------------------------------------------------
// Fused prep: fp32->bf16, 3-bit K-granule swizzle (k ^ (((r>>1)&7)<<3))
// + RoPE cos/sin table. (unchanged, round-13/16)
// ---------------------------------------------------------------------------
__global__ __launch_bounds__(256, 8)
void prep(const float* __restrict__ hidden, const float* __restrict__ Wqkv,
          const float* __restrict__ Wd,
          unsigned short* __restrict__ hidb, unsigned short* __restrict__ wqkvb,
          unsigned short* __restrict__ wdb,
          float* __restrict__ cosT, float* __restrict__ sinT) {
  int bid = blockIdx.x;
  if (bid < 24576) {
    const float* src; unsigned short* dst; int lb;
    if (bid < 8192)       { src = hidden; dst = hidb;  lb = bid; }
    else if (bid < 20480) { src = Wqkv;   dst = wqkvb; lb = bid - 8192; }
    else                  { src = Wd;     dst = wdb;   lb = bid - 20480; }
    int i = lb * 256 + threadIdx.x;
    int base = i << 2;
    int r = base >> 11, k = base & 2047;
    f32x4 v = *(const f32x4*)(src + base);
    int kp = k ^ (((r >> 1) & 7) << 3);
    u16x4 o;
    o[0] = f2bf(v[0]); o[1] = f2bf(v[1]); o[2] = f2bf(v[2]); o[3] = f2bf(v[3]);
    *(u16x4*)(dst + (size_t)r * 2048 + kp) = o;
  } else {
    int idx = (bid - 24576) * 256 + threadIdx.x;   // 2048*64
    int s = idx >> 6, i = idx & 63;
    float inv = powf(1e-4f, (float)i * (1.0f / 64.0f));
    float a = (float)s * inv;
    cosT[idx] = cosf(a);
    sinT[idx] = sinf(a);
  }
}

// ---------------------------------------------------------------------------
// QKV GEMM (round-13/16 best, unchanged): 128x384, BK=64, ring A3/B2,
// 1 barrier/tile, vmcnt(2), split-register upfront reads, fused V-transpose.
// ---------------------------------------------------------------------------
__global__ __launch_bounds__(512, 2)
void gemm_qkv(const unsigned short* __restrict__ A,
              const unsigned short* __restrict__ Bt,
              const float* __restrict__ bias,
              unsigned short* __restrict__ Qs,
              unsigned short* __restrict__ Ks,
              unsigned short* __restrict__ Vt,
              const float* __restrict__ cosT,
              const float* __restrict__ sinT)
{
  __shared__ alignas(16) char lds[147456];   // 144 KiB
  const int tid = threadIdx.x;
  const int wid = tid >> 6, lane = tid & 63, g = lane >> 4, c = lane & 15;
  const int wr = wid >> 2, wc = wid & 3;

  const int bid = blockIdx.x;
  const int swz = (bid & 7) * 64 + (bid >> 3);
  const int nblk = swz & 15, mblk = swz >> 4;
  const int m0 = mblk << 7;
  const int n0 = nblk * 384;
  const int nh = nblk;

  char* ldsb = (char*)lds;
  const int sw = c >> 1;
  const char* ldsA0 = ldsb + (wr * 64 + c) * 128 + ((g ^ sw) << 4);
  const char* ldsA1 = ldsb + (wr * 64 + c) * 128 + (((4 + g) ^ sw) << 4);
  const char* ldsB0 = ldsb + 49152 + (wc * 16 + c) * 128 + ((g ^ sw) << 4);
  const char* ldsB1 = ldsb + 49152 + (wc * 16 + c) * 128 + (((4 + g) ^ sw) << 4);

  const char* gA = (const char*)A  + (size_t)(m0 + (tid >> 3)) * 4096 + (tid & 7) * 16;
  const char* gB = (const char*)Bt + (size_t)(n0 + (tid >> 3)) * 4096 + (tid & 7) * 16;
  char* lA = ldsb + tid * 16;
  char* lB = ldsb + 49152 + tid * 16;

#define STG_A(T, BUF) do { const char* _g = gA + (T) * 128; char* _l = lA + (BUF) * 16384; \
    gl_lds16(_g, _l); gl_lds16(_g + 262144, _l + 8192); } while (0)
#define STG_B(T, BUF) do { const char* _g = gB + (T) * 128; char* _l = lB + (BUF) * 49152; \
    gl_lds16(_g, _l);           gl_lds16(_g + 262144, _l + 8192);   \
    gl_lds16(_g + 524288, _l + 16384); gl_lds16(_g + 786432, _l + 24576); \
    gl_lds16(_g + 1048576, _l + 32768); gl_lds16(_g + 1310720, _l + 40960); } while (0)

  f32x4 acc[4][6];
#pragma unroll
  for (int i = 0; i < 4; ++i)
#pragma unroll
    for (int j = 0; j < 6; ++j) {
      acc[i][j][0] = 0.f; acc[i][j][1] = 0.f; acc[i][j][2] = 0.f; acc[i][j][3] = 0.f;
    }

  bf16x8 a0[4], a1[4], b0[6], b1[6];
  const int NT = KDIM / 64;   // 32

#define TILE(T, SA, SB) do {                                                \
    if ((T) + 1 < NT) { STG_B((T) + 1, ((T) + 1) & 1); }                    \
    if ((T) + 2 < NT) { STG_A((T) + 2, ((T) + 2) % 3); }                    \
    _Pragma("unroll")                                                       \
    for (int mf = 0; mf < 4; ++mf) {                                        \
      a0[mf] = *(const bf16x8*)(ldsA0 + (SA) * 16384 + mf * 2048);          \
      a1[mf] = *(const bf16x8*)(ldsA1 + (SA) * 16384 + mf * 2048);          \
    }                                                                       \
    _Pragma("unroll")                                                       \
    for (int nl = 0; nl < 6; ++nl) {                                        \
      b0[nl] = *(const bf16x8*)(ldsB0 + (SB) * 49152 + nl * 8192);          \
      b1[nl] = *(const bf16x8*)(ldsB1 + (SB) * 49152 + nl * 8192);          \
    }                                                                       \
    __builtin_amdgcn_s_setprio(1);                                          \
    _Pragma("unroll")                                                       \
    for (int mf = 0; mf < 4; ++mf)                                          \
      _Pragma("unroll")                                                     \
      for (int nl = 0; nl < 6; ++nl)                                        \
        acc[mf][nl] = mfma16(a0[mf], b0[nl], acc[mf][nl]);                  \
    _Pragma("unroll")                                                       \
    for (int mf = 0; mf < 4; ++mf)                                          \
      _Pragma("unroll")                                                     \
      for (int nl = 0; nl < 6; ++nl)                                        \
        acc[mf][nl] = mfma16(a1[mf], b1[nl], acc[mf][nl]);                  \
    __builtin_amdgcn_s_setprio(0);                                          \
    if ((T) + 2 < NT) { asm volatile("s_waitcnt vmcnt(2)" ::: "memory"); }  \
    else              { asm volatile("s_waitcnt vmcnt(0)" ::: "memory"); }  \
    __builtin_amdgcn_s_barrier();                                           \
  } while (0)

  STG_B(0, 0); STG_A(0, 0); STG_A(1, 1);
  asm volatile("s_waitcnt vmcnt(2)" ::: "memory");
  __builtin_amdgcn_s_barrier();

  for (int t = 0; t < 30; t += 6) {
    TILE(t + 0, 0, 0);
    TILE(t + 1, 1, 1);
    TILE(t + 2, 2, 0);
    TILE(t + 3, 0, 1);
    TILE(t + 4, 1, 0);
    TILE(t + 5, 2, 1);
  }
  TILE(30, 0, 0);
  TILE(31, 1, 1);

  const float qsc = 0.08838834764831845f * 1.4426950408889634f;
  const int dl = wc * 16 + c;
  unsigned short* Vtmp = (unsigned short*)ldsb;
  const int s0 = m0 >> 1;
#pragma unroll
  for (int ar = 0; ar < 4; ++ar) {
#pragma unroll
    for (int rr = 0; rr < 4; ++rr) {
      int m = m0 + wr * 64 + ar * 16 + g * 4 + rr;
      int s = m >> 1, bb = m & 1;
      size_t plane = (size_t)(bb * NHEAD + nh) * (SEQ * HDIM);
      int swb = (s & 7) << 3;
      float co = cosT[s * 64 + dl], si = sinT[s * 64 + dl];
      {
        float xl = acc[ar][0][rr] + bias[n0 + dl];
        float xr = acc[ar][1][rr] + bias[n0 + 64 + dl];
        Qs[plane + (size_t)s * HDIM + (dl ^ swb)]        = f2bf((co * xl - si * xr) * qsc);
        Qs[plane + (size_t)s * HDIM + ((dl + 64) ^ swb)] = f2bf((si * xl + co * xr) * qsc);
      }
      {
        float xl = acc[ar][2][rr] + bias[n0 + 128 + dl];
        float xr = acc[ar][3][rr] + bias[n0 + 192 + dl];
        Ks[plane + (size_t)s * HDIM + (dl ^ swb)]        = f2bf(co * xl - si * xr);
        Ks[plane + (size_t)s * HDIM + ((dl + 64) ^ swb)] = f2bf(si * xl + co * xr);
      }
      {
        int sloc = s - s0;
        Vtmp[(bb * 64 + sloc) * 136 + dl]      = f2bf(acc[ar][4][rr] + bias[n0 + 256 + dl]);
        Vtmp[(bb * 64 + sloc) * 136 + dl + 64] = f2bf(acc[ar][5][rr] + bias[n0 + 320 + dl]);
      }
    }
  }
  __syncthreads();
  {
    int b2 = tid >> 8, r = tid & 255;
    int d = r >> 1, half = r & 1;
    size_t planeV = (size_t)(b2 * NHEAD + nh) * (SEQ * HDIM);
    unsigned short* dstp = Vt + planeV + (size_t)d * SEQ + s0;
    int swb = (d & 7) << 3;
#pragma unroll
    for (int gg = 0; gg < 4; ++gg) {
      u16x8 v;
#pragma unroll
      for (int e = 0; e < 8; ++e)
        v[e] = Vtmp[(b2 * 64 + half * 32 + gg * 8 + e) * 136 + d];
      int tloc = half * 32 + gg * 8;
      *(u16x8*)(dstp + (tloc ^ swb)) = v;
    }
  }
#undef TILE
#undef STG_A
#undef STG_B
}

// ---------------------------------------------------------------------------
// Dense projection GEMM (round-13/16, unchanged): 128x256, BK=64, ring-3,
// 1 barrier/tile, vmcnt(6), split-register upfront reads.
// ---------------------------------------------------------------------------
__global__ __launch_bounds__(512, 2)
void gemm_out(const unsigned short* __restrict__ A,
              const unsigned short* __restrict__ Bt,
              const float* __restrict__ bias,
              float* __restrict__ Cout)
{
  __shared__ alignas(16) char lds[147456];   // 144 KiB
  const int tid = threadIdx.x;
  const int wid = tid >> 6, lane = tid & 63, g = lane >> 4, c = lane & 15;
  const int wr = wid >> 2, wc = wid & 3;

  const int bid = blockIdx.x;
  const int swz = (bid & 7) * 32 + (bid >> 3);
  const int nblk = swz >> 5, mblk = swz & 31;
  const int m0 = mblk << 7, n0 = nblk << 8;

  char* ldsb = (char*)lds;
  const int sw = c >> 1;
  const char* ldsA0 = ldsb + (wr * 64 + c) * 128 + ((g ^ sw) << 4);
  const char* ldsA1 = ldsb + (wr * 64 + c) * 128 + (((4 + g) ^ sw) << 4);
  const char* ldsB0 = ldsb + 49152 + (wc * 64 + c) * 128 + ((g ^ sw) << 4);
  const char* ldsB1 = ldsb + 49152 + (wc * 64 + c) * 128 + (((4 + g) ^ sw) << 4);

  const char* gA = (const char*)A  + (size_t)(m0 + (tid >> 3)) * 4096 + (tid & 7) * 16;
  const char* gB = (const char*)Bt + (size_t)(n0 + (tid >> 3)) * 4096 + (tid & 7) * 16;
  char* lA = ldsb + tid * 16;
  char* lB = ldsb + 49152 + tid * 16;

#define STG_A(T, BUF) do { const char* _g = gA + (T) * 128; char* _l = lA + (BUF) * 16384; \
    gl_lds16(_g, _l); gl_lds16(_g + 262144, _l + 8192); } while (0)
#define STG_B(T, BUF) do { const char* _g = gB + (T) * 128; char* _l = lB + (BUF) * 32768; \
    gl_lds16(_g, _l);           gl_lds16(_g + 262144, _l + 8192);   \
    gl_lds16(_g + 524288, _l + 16384); gl_lds16(_g + 786432, _l + 24576); } while (0)

  f32x4 acc[4][4];
#pragma unroll
  for (int i = 0; i < 4; ++i)
#pragma unroll
    for (int j = 0; j < 4; ++j) {
      acc[i][j][0] = 0.f; acc[i][j][1] = 0.f; acc[i][j][2] = 0.f; acc[i][j][3] = 0.f;
    }

  bf16x8 a0[4], a1[4], b0[4], b1[4];
  const int NT = KDIM / 64;   // 32

#define TILE(T, S) do {                                                     \
    if ((T) + 2 < NT) { STG_B((T) + 2, ((T) + 2) % 3); STG_A((T) + 2, ((T) + 2) % 3); } \
    _Pragma("unroll")                                                       \
    for (int mf = 0; mf < 4; ++mf) {                                        \
      a0[mf] = *(const bf16x8*)(ldsA0 + (S) * 16384 + mf * 2048);           \
      a1[mf] = *(const bf16x8*)(ldsA1 + (S) * 16384 + mf * 2048);           \
    }                                                                       \
    _Pragma("unroll")                                                       \
    for (int nl = 0; nl < 4; ++nl) {                                        \
      b0[nl] = *(const bf16x8*)(ldsB0 + (S) * 32768 + nl * 2048);           \
      b1[nl] = *(const bf16x8*)(ldsB1 + (S) * 32768 + nl * 2048);           \
    }                                                                       \
    __builtin_amdgcn_s_setprio(1);                                          \
    _Pragma("unroll")                                                       \
    for (int mf = 0; mf < 4; ++mf)                                          \
      _Pragma("unroll")                                                     \
      for (int nl = 0; nl < 4; ++nl)                                        \
        acc[mf][nl] = mfma16(a0[mf], b0[nl], acc[mf][nl]);                  \
    _Pragma("unroll")                                                       \
    for (int mf = 0; mf < 4; ++mf)                                          \
      _Pragma("unroll")                                                     \
      for (int nl = 0; nl < 4; ++nl)                                        \
        acc[mf][nl] = mfma16(a1[mf], b1[nl], acc[mf][nl]);                  \
    __builtin_amdgcn_s_setprio(0);                                          \
    if ((T) + 2 < NT) { asm volatile("s_waitcnt vmcnt(6)" ::: "memory"); }  \
    else              { asm volatile("s_waitcnt vmcnt(0)" ::: "memory"); }  \
    __builtin_amdgcn_s_barrier();                                           \
  } while (0)

  STG_B(0, 0); STG_A(0, 0);
  STG_B(1, 1); STG_A(1, 1);
  asm volatile("s_waitcnt vmcnt(6)" ::: "memory");
  __builtin_amdgcn_s_barrier();

  for (int t = 0; t < 30; t += 3) {
    TILE(t, 0);
    TILE(t + 1, 1);
    TILE(t + 2, 2);
  }
  TILE(30, 0);
  TILE(31, 1);

#pragma unroll
  for (int mf = 0; mf < 4; ++mf)
#pragma unroll
    for (int rr = 0; rr < 4; ++rr) {
      int m = m0 + wr * 64 + mf * 16 + g * 4 + rr;
#pragma unroll
      for (int nl = 0; nl < 4; ++nl) {
        int n = n0 + wc * 64 + nl * 16 + c;
        Cout[(size_t)m * HID + n] = acc[mf][nl][rr] + bias[n];
      }
    }
#undef TILE
#undef STG_A
#undef STG_B
}

// ---------------------------------------------------------------------------
// Flash attention, RE-SHARDED FOR OCCUPANCY: 512 blocks x 256 threads
// (4 waves own one 128-row q-block; heavy-qb-first). LDS = K dbuf 32K +
// V 16K + P 18K = 66 KiB -> TWO independent blocks/CU whose barrier groups
// interleave (cross-block overlap of staging drains and compute).
// Same math/layouts as the round-16 version.
// ---------------------------------------------------------------------------
__global__ __launch_bounds__(256, 2)
void attn(const unsigned short* __restrict__ Qs,
          const unsigned short* __restrict__ Ks,
          const unsigned short* __restrict__ Vt,
          unsigned short* __restrict__ ctx)
{
  __shared__ alignas(16) unsigned short Klds[2][64 * 128];   // 2 x 16 KiB
  __shared__ alignas(16) unsigned short Vlds[128 * 64];      // 16 KiB
  __shared__ alignas(16) unsigned short Plds[128 * 72];      // 18 KiB
  const int tid = threadIdx.x;
  const int w = tid >> 6, lane = tid & 63, g = lane >> 4, c = lane & 15;
  const int bid = blockIdx.x;
  const int head = bid & 31;
  const int qb = 15 - (bid >> 5);         // heavy first
  const int q0w = (qb << 7) + w * 32;
  const size_t plane = (size_t)head * (SEQ * HDIM);
  const unsigned short* Qp = Qs + plane;

  bf16x8 qf[2][4];
#pragma unroll
  for (int q2 = 0; q2 < 2; ++q2) {
    int s = q0w + q2 * 16 + c;
    int swb = (s & 7) << 3;
#pragma unroll
    for (int kk = 0; kk < 4; ++kk) {
      int d0 = kk * 32 + g * 8;
      qf[q2][kk] = *(const bf16x8*)(Qp + (size_t)s * HDIM + (d0 ^ swb));
    }
  }

  f32x4 accO[2][8];
#pragma unroll
  for (int i = 0; i < 2; ++i)
#pragma unroll
    for (int jj = 0; jj < 8; ++jj) {
      accO[i][jj][0] = 0.f; accO[i][jj][1] = 0.f; accO[i][jj][2] = 0.f; accO[i][jj][3] = 0.f;
    }
  float mrun[2] = { -1e30f, -1e30f };
  float lrun[2] = { 0.f, 0.f };

  // 256-thread staging: 4 ops per 16KB tile
  const char* Kg = (const char*)(Ks + plane) + (tid >> 4) * 256 + (tid & 15) * 16;
  const char* Vg = (const char*)(Vt + plane) + (size_t)(tid >> 3) * 4096 + (tid & 7) * 16;

  const int ntiles = (qb << 1) + 2;
  const int qminw = q0w;
  const int qmaxw = q0w + 31;

#define STG_K(T, BUF) do { char* _kd = (char*)Klds[BUF] + tid * 16;           \
    const char* _kg = Kg + (size_t)(T) * 16384;                               \
    gl_lds16(_kg, _kd);             gl_lds16(_kg + 4096,  _kd + 4096);        \
    gl_lds16(_kg + 8192, _kd + 8192); gl_lds16(_kg + 12288, _kd + 12288); } while (0)
#define STG_V(T) do { char* _vd = (char*)Vlds + tid * 16;                     \
    const char* _vg = Vg + (T) * 128;                                         \
    gl_lds16(_vg, _vd);               gl_lds16(_vg + 131072, _vd + 4096);     \
    gl_lds16(_vg + 262144, _vd + 8192); gl_lds16(_vg + 393216, _vd + 12288); } while (0)

  STG_K(0, 0);

  for (int kt = 0; kt < ntiles; ++kt) {
    const int t0 = kt << 6;
    const bool havenext = (kt + 1 < ntiles);

    STG_V(kt);
    if (havenext) STG_K(kt + 1, (kt + 1) & 1);
    // K(kt) landed; V(kt)+K(kt+1) (8 ops) stay in flight
    if (havenext) asm volatile("s_waitcnt vmcnt(8)" ::: "memory");
    else          asm volatile("s_waitcnt vmcnt(4)" ::: "memory");
    __builtin_amdgcn_s_barrier();

    if (t0 <= qmaxw) {
      const char* Kb = (const char*)Klds[kt & 1];
      f32x4 sacc[4][2];
#pragma unroll
      for (int i = 0; i < 4; ++i)
#pragma unroll
        for (int jj = 0; jj < 2; ++jj) {
          sacc[i][jj][0] = 0.f; sacc[i][jj][1] = 0.f; sacc[i][jj][2] = 0.f; sacc[i][jj][3] = 0.f;
        }
      __builtin_amdgcn_s_setprio(1);
#pragma unroll
      for (int kk = 0; kk < 4; ++kk) {
        bf16x8 kf[4];
#pragma unroll
        for (int ta = 0; ta < 4; ++ta) {
          int t = ta * 16 + c;
          int d0 = kk * 32 + g * 8;
          kf[ta] = *(const bf16x8*)(Kb + t * 256 + ((d0 ^ ((t & 7) << 3)) << 1));
        }
#pragma unroll
        for (int ta = 0; ta < 4; ++ta)
#pragma unroll
          for (int q2 = 0; q2 < 2; ++q2)
            sacc[ta][q2] = mfma16(kf[ta], qf[q2][kk], sacc[ta][q2]);
      }
      __builtin_amdgcn_s_setprio(0);

      if (t0 + 63 > qminw) {
#pragma unroll
        for (int ta = 0; ta < 4; ++ta)
#pragma unroll
          for (int q2 = 0; q2 < 2; ++q2)
#pragma unroll
            for (int r = 0; r < 4; ++r) {
              int t = t0 + ta * 16 + g * 4 + r;
              int q = qminw + q2 * 16 + c;
              if (t > q) sacc[ta][q2][r] = -30000.f;
            }
      }

      float corr[2];
      bool resc = false;
#pragma unroll
      for (int q2 = 0; q2 < 2; ++q2) {
        float mx = -30000.f;
#pragma unroll
        for (int ta = 0; ta < 4; ++ta)
          mx = fmaxf(mx, fmaxf(fmaxf(sacc[ta][q2][0], sacc[ta][q2][1]),
                               fmaxf(sacc[ta][q2][2], sacc[ta][q2][3])));
        mx = fmaxf(mx, __shfl_xor(mx, 16));
        mx = fmaxf(mx, __shfl_xor(mx, 32));
        bool rs = mx > mrun[q2] + 8.0f;
        resc |= rs;
        float mnew = rs ? mx : mrun[q2];
        corr[q2] = fexp2(mrun[q2] - mnew);
        mrun[q2] = mnew;
        float ls = 0.f;
#pragma unroll
        for (int ta = 0; ta < 4; ++ta)
#pragma unroll
          for (int r = 0; r < 4; ++r) {
            float e = fexp2(sacc[ta][q2][r] - mnew);
            sacc[ta][q2][r] = e;
            ls += e;
          }
        ls += __shfl_xor(ls, 16);
        ls += __shfl_xor(ls, 32);
        lrun[q2] = lrun[q2] * corr[q2] + ls;
      }

      if (__any(resc)) {
#pragma unroll
        for (int q2 = 0; q2 < 2; ++q2)
#pragma unroll
          for (int r = 0; r < 4; ++r) {
            float cD = __shfl(corr[q2], (lane & 48) | (((lane >> 4) << 2) + r));
#pragma unroll
            for (int fn = 0; fn < 8; ++fn) accO[q2][fn][r] *= cD;
          }
      }

#pragma unroll
      for (int q2 = 0; q2 < 2; ++q2) {
        int prow = w * 32 + q2 * 16 + c;
#pragma unroll
        for (int ta = 0; ta < 4; ++ta) {
          u16x4 pk;
          pk[0] = f2bf(sacc[ta][q2][0]); pk[1] = f2bf(sacc[ta][q2][1]);
          pk[2] = f2bf(sacc[ta][q2][2]); pk[3] = f2bf(sacc[ta][q2][3]);
          *(u16x4*)(&Plds[prow * 72 + ta * 16 + g * 4]) = pk;
        }
      }
    }

    if (havenext) asm volatile("s_waitcnt vmcnt(4)" ::: "memory");
    else          asm volatile("s_waitcnt vmcnt(0)" ::: "memory");
    __builtin_amdgcn_s_barrier();

    if (t0 <= qmaxw) {
      __builtin_amdgcn_s_setprio(1);
#pragma unroll
      for (int kk = 0; kk < 2; ++kk) {
        bf16x8 pa[2];
#pragma unroll
        for (int q2 = 0; q2 < 2; ++q2)
          pa[q2] = *(const bf16x8*)((const char*)Plds + (w * 32 + q2 * 16 + c) * 144 + (kk * 32 + g * 8) * 2);
#pragma unroll
        for (int fn = 0; fn < 8; ++fn) {
          int d = fn * 16 + c;
          int tt = kk * 32 + g * 8;
          bf16x8 vb = *(const bf16x8*)((const char*)Vlds + d * 128 + ((tt ^ ((d & 7) << 3)) << 1));
#pragma unroll
          for (int q2 = 0; q2 < 2; ++q2)
            accO[q2][fn] = mfma16(pa[q2], vb, accO[q2][fn]);
        }
      }
      __builtin_amdgcn_s_setprio(0);
    }
    __builtin_amdgcn_s_barrier();
  }
#undef STG_K
#undef STG_V

  const int b = head >> 4, nh = head & 15;
  float linv[2] = { 1.0f / lrun[0], 1.0f / lrun[1] };
#pragma unroll
  for (int q2 = 0; q2 < 2; ++q2)
#pragma unroll
    for (int r = 0; r < 4; ++r) {
      float inv = __shfl(linv[q2], (lane & 48) | (((lane >> 4) << 2) + r));
      int q = q0w + q2 * 16 + g * 4 + r;
      int m = q * 2 + b;
      int swb = ((m >> 1) & 7) << 3;
#pragma unroll
      for (int fn = 0; fn < 8; ++fn) {
        int h = nh * 128 + fn * 16 + c;
        ctx[(size_t)m * HID + (h ^ swb)] = f2bf(accO[q2][fn][r] * inv);
      }
    }
}

extern "C" void kernel_launch(void* const* d_in, const int* in_sizes, int n_in,
                              void* d_out, int out_size, void* d_ws, size_t ws_size,
                              hipStream_t stream) {
  const float* hidden = (const float*)d_in[0];
  const float* Wqkv = (const float*)d_in[2];
  const float* bqkv = (const float*)d_in[3];
  const float* Wd   = (const float*)d_in[4];
  const float* bd   = (const float*)d_in[5];
  float* out = (float*)d_out;
  char* ws = (char*)d_ws;

  const size_t OFF_HID  = 0;
  const size_t OFF_WQKV = 16777216;
  const size_t OFF_WD   = 41943040;
  const size_t OFF_COS  = 50331648;
  const size_t OFF_SIN  = 50855936;
  const size_t OFF_Q    = 51380224;
  const size_t OFF_K    = 68157440;
  const size_t OFF_VT   = 84934656;
  if (ws_size < 101711872) return;

  unsigned short* hidb  = (unsigned short*)(ws + OFF_HID);
  unsigned short* wqkvb = (unsigned short*)(ws + OFF_WQKV);
  unsigned short* wdb   = (unsigned short*)(ws + OFF_WD);
  float* cosT = (float*)(ws + OFF_COS);
  float* sinT = (float*)(ws + OFF_SIN);
  unsigned short* Qsb = (unsigned short*)(ws + OFF_Q);
  unsigned short* Ksb = (unsigned short*)(ws + OFF_K);
  unsigned short* Vtb = (unsigned short*)(ws + OFF_VT);
  unsigned short* ctxb = hidb;

  prep<<<25088, 256, 0, stream>>>(hidden, Wqkv, Wd, hidb, wqkvb, wdb, cosT, sinT);

  gemm_qkv<<<512, 512, 0, stream>>>(hidb, wqkvb, bqkv, Qsb, Ksb, Vtb, cosT, sinT);
  attn<<<512, 256, 0, stream>>>(Qsb, Ksb, Vtb, ctxb);
  gemm_out<<<256, 512, 0, stream>>>(ctxb, wdb, bd, out);
}

// Round 18
// 224.554 us; speedup vs baseline: 1.0415x; 1.0415x over previous
//
#include <hip/hip_runtime.h>

#define SEQ   2048
#define BATCH 2
#define HID   2048
#define NHEAD 16
#define HDIM  128
#define MTOT  4096
#define KDIM  2048

typedef __attribute__((ext_vector_type(8))) short  bf16x8;
typedef __attribute__((ext_vector_type(4))) float  f32x4;
typedef __attribute__((ext_vector_type(4))) unsigned short u16x4;
typedef __attribute__((ext_vector_type(8))) unsigned short u16x8;

__device__ __forceinline__ unsigned short f2bf(float x) {
  unsigned u = __float_as_uint(x);
  u += 0x7fffu + ((u >> 16) & 1u);
  return (unsigned short)(u >> 16);
}

__device__ __forceinline__ float fexp2(float x) {
  float r;
  asm("v_exp_f32 %0, %1" : "=v"(r) : "v"(x));
  return r;
}

__device__ __forceinline__ void gl_lds16(const void* g, void* l) {
  __builtin_amdgcn_global_load_lds(
      (__attribute__((address_space(1))) void*)g,
      (__attribute__((address_space(3))) void*)l, 16, 0, 0);
}

__device__ __forceinline__ f32x4 mfma16(bf16x8 a, bf16x8 b, f32x4 c) {
  return __builtin_amdgcn_mfma_f32_16x16x32_bf16(a, b, c, 0, 0, 0);
}

// ---------------------------------------------------------------------------
// Fused prep: fp32->bf16, 3-bit K-granule swizzle (k ^ (((r>>1)&7)<<3))
// + RoPE cos/sin table. (unchanged)
// ---------------------------------------------------------------------------
__global__ __launch_bounds__(256, 8)
void prep(const float* __restrict__ hidden, const float* __restrict__ Wqkv,
          const float* __restrict__ Wd,
          unsigned short* __restrict__ hidb, unsigned short* __restrict__ wqkvb,
          unsigned short* __restrict__ wdb,
          float* __restrict__ cosT, float* __restrict__ sinT) {
  int bid = blockIdx.x;
  if (bid < 24576) {
    const float* src; unsigned short* dst; int lb;
    if (bid < 8192)       { src = hidden; dst = hidb;  lb = bid; }
    else if (bid < 20480) { src = Wqkv;   dst = wqkvb; lb = bid - 8192; }
    else                  { src = Wd;     dst = wdb;   lb = bid - 20480; }
    int i = lb * 256 + threadIdx.x;
    int base = i << 2;
    int r = base >> 11, k = base & 2047;
    f32x4 v = *(const f32x4*)(src + base);
    int kp = k ^ (((r >> 1) & 7) << 3);
    u16x4 o;
    o[0] = f2bf(v[0]); o[1] = f2bf(v[1]); o[2] = f2bf(v[2]); o[3] = f2bf(v[3]);
    *(u16x4*)(dst + (size_t)r * 2048 + kp) = o;
  } else {
    int idx = (bid - 24576) * 256 + threadIdx.x;   // 2048*64
    int s = idx >> 6, i = idx & 63;
    float inv = powf(1e-4f, (float)i * (1.0f / 64.0f));
    float a = (float)s * inv;
    cosT[idx] = cosf(a);
    sinT[idx] = sinf(a);
  }
}

// ---------------------------------------------------------------------------
// QKV GEMM (round-13/16 best, unchanged): 128x384, BK=64, ring A3/B2,
// 1 barrier/tile, vmcnt(2), split-register upfront reads, fused V-transpose.
// ---------------------------------------------------------------------------
__global__ __launch_bounds__(512, 2)
void gemm_qkv(const unsigned short* __restrict__ A,
              const unsigned short* __restrict__ Bt,
              const float* __restrict__ bias,
              unsigned short* __restrict__ Qs,
              unsigned short* __restrict__ Ks,
              unsigned short* __restrict__ Vt,
              const float* __restrict__ cosT,
              const float* __restrict__ sinT)
{
  __shared__ alignas(16) char lds[147456];   // 144 KiB
  const int tid = threadIdx.x;
  const int wid = tid >> 6, lane = tid & 63, g = lane >> 4, c = lane & 15;
  const int wr = wid >> 2, wc = wid & 3;

  const int bid = blockIdx.x;
  const int swz = (bid & 7) * 64 + (bid >> 3);
  const int nblk = swz & 15, mblk = swz >> 4;
  const int m0 = mblk << 7;
  const int n0 = nblk * 384;
  const int nh = nblk;

  char* ldsb = (char*)lds;
  const int sw = c >> 1;
  const char* ldsA0 = ldsb + (wr * 64 + c) * 128 + ((g ^ sw) << 4);
  const char* ldsA1 = ldsb + (wr * 64 + c) * 128 + (((4 + g) ^ sw) << 4);
  const char* ldsB0 = ldsb + 49152 + (wc * 16 + c) * 128 + ((g ^ sw) << 4);
  const char* ldsB1 = ldsb + 49152 + (wc * 16 + c) * 128 + (((4 + g) ^ sw) << 4);

  const char* gA = (const char*)A  + (size_t)(m0 + (tid >> 3)) * 4096 + (tid & 7) * 16;
  const char* gB = (const char*)Bt + (size_t)(n0 + (tid >> 3)) * 4096 + (tid & 7) * 16;
  char* lA = ldsb + tid * 16;
  char* lB = ldsb + 49152 + tid * 16;

#define STG_A(T, BUF) do { const char* _g = gA + (T) * 128; char* _l = lA + (BUF) * 16384; \
    gl_lds16(_g, _l); gl_lds16(_g + 262144, _l + 8192); } while (0)
#define STG_B(T, BUF) do { const char* _g = gB + (T) * 128; char* _l = lB + (BUF) * 49152; \
    gl_lds16(_g, _l);           gl_lds16(_g + 262144, _l + 8192);   \
    gl_lds16(_g + 524288, _l + 16384); gl_lds16(_g + 786432, _l + 24576); \
    gl_lds16(_g + 1048576, _l + 32768); gl_lds16(_g + 1310720, _l + 40960); } while (0)

  f32x4 acc[4][6];
#pragma unroll
  for (int i = 0; i < 4; ++i)
#pragma unroll
    for (int j = 0; j < 6; ++j) {
      acc[i][j][0] = 0.f; acc[i][j][1] = 0.f; acc[i][j][2] = 0.f; acc[i][j][3] = 0.f;
    }

  bf16x8 a0[4], a1[4], b0[6], b1[6];
  const int NT = KDIM / 64;   // 32

#define TILE(T, SA, SB) do {                                                \
    if ((T) + 1 < NT) { STG_B((T) + 1, ((T) + 1) & 1); }                    \
    if ((T) + 2 < NT) { STG_A((T) + 2, ((T) + 2) % 3); }                    \
    _Pragma("unroll")                                                       \
    for (int mf = 0; mf < 4; ++mf) {                                        \
      a0[mf] = *(const bf16x8*)(ldsA0 + (SA) * 16384 + mf * 2048);          \
      a1[mf] = *(const bf16x8*)(ldsA1 + (SA) * 16384 + mf * 2048);          \
    }                                                                       \
    _Pragma("unroll")                                                       \
    for (int nl = 0; nl < 6; ++nl) {                                        \
      b0[nl] = *(const bf16x8*)(ldsB0 + (SB) * 49152 + nl * 8192);          \
      b1[nl] = *(const bf16x8*)(ldsB1 + (SB) * 49152 + nl * 8192);          \
    }                                                                       \
    __builtin_amdgcn_s_setprio(1);                                          \
    _Pragma("unroll")                                                       \
    for (int mf = 0; mf < 4; ++mf)                                          \
      _Pragma("unroll")                                                     \
      for (int nl = 0; nl < 6; ++nl)                                        \
        acc[mf][nl] = mfma16(a0[mf], b0[nl], acc[mf][nl]);                  \
    _Pragma("unroll")                                                       \
    for (int mf = 0; mf < 4; ++mf)                                          \
      _Pragma("unroll")                                                     \
      for (int nl = 0; nl < 6; ++nl)                                        \
        acc[mf][nl] = mfma16(a1[mf], b1[nl], acc[mf][nl]);                  \
    __builtin_amdgcn_s_setprio(0);                                          \
    if ((T) + 2 < NT) { asm volatile("s_waitcnt vmcnt(2)" ::: "memory"); }  \
    else              { asm volatile("s_waitcnt vmcnt(0)" ::: "memory"); }  \
    __builtin_amdgcn_s_barrier();                                           \
  } while (0)

  STG_B(0, 0); STG_A(0, 0); STG_A(1, 1);
  asm volatile("s_waitcnt vmcnt(2)" ::: "memory");
  __builtin_amdgcn_s_barrier();

  for (int t = 0; t < 30; t += 6) {
    TILE(t + 0, 0, 0);
    TILE(t + 1, 1, 1);
    TILE(t + 2, 2, 0);
    TILE(t + 3, 0, 1);
    TILE(t + 4, 1, 0);
    TILE(t + 5, 2, 1);
  }
  TILE(30, 0, 0);
  TILE(31, 1, 1);

  const float qsc = 0.08838834764831845f * 1.4426950408889634f;
  const int dl = wc * 16 + c;
  unsigned short* Vtmp = (unsigned short*)ldsb;
  const int s0 = m0 >> 1;
#pragma unroll
  for (int ar = 0; ar < 4; ++ar) {
#pragma unroll
    for (int rr = 0; rr < 4; ++rr) {
      int m = m0 + wr * 64 + ar * 16 + g * 4 + rr;
      int s = m >> 1, bb = m & 1;
      size_t plane = (size_t)(bb * NHEAD + nh) * (SEQ * HDIM);
      int swb = (s & 7) << 3;
      float co = cosT[s * 64 + dl], si = sinT[s * 64 + dl];
      {
        float xl = acc[ar][0][rr] + bias[n0 + dl];
        float xr = acc[ar][1][rr] + bias[n0 + 64 + dl];
        Qs[plane + (size_t)s * HDIM + (dl ^ swb)]        = f2bf((co * xl - si * xr) * qsc);
        Qs[plane + (size_t)s * HDIM + ((dl + 64) ^ swb)] = f2bf((si * xl + co * xr) * qsc);
      }
      {
        float xl = acc[ar][2][rr] + bias[n0 + 128 + dl];
        float xr = acc[ar][3][rr] + bias[n0 + 192 + dl];
        Ks[plane + (size_t)s * HDIM + (dl ^ swb)]        = f2bf(co * xl - si * xr);
        Ks[plane + (size_t)s * HDIM + ((dl + 64) ^ swb)] = f2bf(si * xl + co * xr);
      }
      {
        int sloc = s - s0;
        Vtmp[(bb * 64 + sloc) * 136 + dl]      = f2bf(acc[ar][4][rr] + bias[n0 + 256 + dl]);
        Vtmp[(bb * 64 + sloc) * 136 + dl + 64] = f2bf(acc[ar][5][rr] + bias[n0 + 320 + dl]);
      }
    }
  }
  __syncthreads();
  {
    int b2 = tid >> 8, r = tid & 255;
    int d = r >> 1, half = r & 1;
    size_t planeV = (size_t)(b2 * NHEAD + nh) * (SEQ * HDIM);
    unsigned short* dstp = Vt + planeV + (size_t)d * SEQ + s0;
    int swb = (d & 7) << 3;
#pragma unroll
    for (int gg = 0; gg < 4; ++gg) {
      u16x8 v;
#pragma unroll
      for (int e = 0; e < 8; ++e)
        v[e] = Vtmp[(b2 * 64 + half * 32 + gg * 8 + e) * 136 + d];
      int tloc = half * 32 + gg * 8;
      *(u16x8*)(dstp + (tloc ^ swb)) = v;
    }
  }
#undef TILE
#undef STG_A
#undef STG_B
}

// ---------------------------------------------------------------------------
// Dense projection GEMM (round-13/16, unchanged): 128x256, BK=64, ring-3,
// 1 barrier/tile, vmcnt(6), split-register upfront reads.
// ---------------------------------------------------------------------------
__global__ __launch_bounds__(512, 2)
void gemm_out(const unsigned short* __restrict__ A,
              const unsigned short* __restrict__ Bt,
              const float* __restrict__ bias,
              float* __restrict__ Cout)
{
  __shared__ alignas(16) char lds[147456];   // 144 KiB
  const int tid = threadIdx.x;
  const int wid = tid >> 6, lane = tid & 63, g = lane >> 4, c = lane & 15;
  const int wr = wid >> 2, wc = wid & 3;

  const int bid = blockIdx.x;
  const int swz = (bid & 7) * 32 + (bid >> 3);
  const int nblk = swz >> 5, mblk = swz & 31;
  const int m0 = mblk << 7, n0 = nblk << 8;

  char* ldsb = (char*)lds;
  const int sw = c >> 1;
  const char* ldsA0 = ldsb + (wr * 64 + c) * 128 + ((g ^ sw) << 4);
  const char* ldsA1 = ldsb + (wr * 64 + c) * 128 + (((4 + g) ^ sw) << 4);
  const char* ldsB0 = ldsb + 49152 + (wc * 64 + c) * 128 + ((g ^ sw) << 4);
  const char* ldsB1 = ldsb + 49152 + (wc * 64 + c) * 128 + (((4 + g) ^ sw) << 4);

  const char* gA = (const char*)A  + (size_t)(m0 + (tid >> 3)) * 4096 + (tid & 7) * 16;
  const char* gB = (const char*)Bt + (size_t)(n0 + (tid >> 3)) * 4096 + (tid & 7) * 16;
  char* lA = ldsb + tid * 16;
  char* lB = ldsb + 49152 + tid * 16;

#define STG_A(T, BUF) do { const char* _g = gA + (T) * 128; char* _l = lA + (BUF) * 16384; \
    gl_lds16(_g, _l); gl_lds16(_g + 262144, _l + 8192); } while (0)
#define STG_B(T, BUF) do { const char* _g = gB + (T) * 128; char* _l = lB + (BUF) * 32768; \
    gl_lds16(_g, _l);           gl_lds16(_g + 262144, _l + 8192);   \
    gl_lds16(_g + 524288, _l + 16384); gl_lds16(_g + 786432, _l + 24576); } while (0)

  f32x4 acc[4][4];
#pragma unroll
  for (int i = 0; i < 4; ++i)
#pragma unroll
    for (int j = 0; j < 4; ++j) {
      acc[i][j][0] = 0.f; acc[i][j][1] = 0.f; acc[i][j][2] = 0.f; acc[i][j][3] = 0.f;
    }

  bf16x8 a0[4], a1[4], b0[4], b1[4];
  const int NT = KDIM / 64;   // 32

#define TILE(T, S) do {                                                     \
    if ((T) + 2 < NT) { STG_B((T) + 2, ((T) + 2) % 3); STG_A((T) + 2, ((T) + 2) % 3); } \
    _Pragma("unroll")                                                       \
    for (int mf = 0; mf < 4; ++mf) {                                        \
      a0[mf] = *(const bf16x8*)(ldsA0 + (S) * 16384 + mf * 2048);           \
      a1[mf] = *(const bf16x8*)(ldsA1 + (S) * 16384 + mf * 2048);           \
    }                                                                       \
    _Pragma("unroll")                                                       \
    for (int nl = 0; nl < 4; ++nl) {                                        \
      b0[nl] = *(const bf16x8*)(ldsB0 + (S) * 32768 + nl * 2048);           \
      b1[nl] = *(const bf16x8*)(ldsB1 + (S) * 32768 + nl * 2048);           \
    }                                                                       \
    __builtin_amdgcn_s_setprio(1);                                          \
    _Pragma("unroll")                                                       \
    for (int mf = 0; mf < 4; ++mf)                                          \
      _Pragma("unroll")                                                     \
      for (int nl = 0; nl < 4; ++nl)                                        \
        acc[mf][nl] = mfma16(a0[mf], b0[nl], acc[mf][nl]);                  \
    _Pragma("unroll")                                                       \
    for (int mf = 0; mf < 4; ++mf)                                          \
      _Pragma("unroll")                                                     \
      for (int nl = 0; nl < 4; ++nl)                                        \
        acc[mf][nl] = mfma16(a1[mf], b1[nl], acc[mf][nl]);                  \
    __builtin_amdgcn_s_setprio(0);                                          \
    if ((T) + 2 < NT) { asm volatile("s_waitcnt vmcnt(6)" ::: "memory"); }  \
    else              { asm volatile("s_waitcnt vmcnt(0)" ::: "memory"); }  \
    __builtin_amdgcn_s_barrier();                                           \
  } while (0)

  STG_B(0, 0); STG_A(0, 0);
  STG_B(1, 1); STG_A(1, 1);
  asm volatile("s_waitcnt vmcnt(6)" ::: "memory");
  __builtin_amdgcn_s_barrier();

  for (int t = 0; t < 30; t += 3) {
    TILE(t, 0);
    TILE(t + 1, 1);
    TILE(t + 2, 2);
  }
  TILE(30, 0);
  TILE(31, 1);

#pragma unroll
  for (int mf = 0; mf < 4; ++mf)
#pragma unroll
    for (int rr = 0; rr < 4; ++rr) {
      int m = m0 + wr * 64 + mf * 16 + g * 4 + rr;
#pragma unroll
      for (int nl = 0; nl < 4; ++nl) {
        int n = n0 + wc * 64 + nl * 16 + c;
        Cout[(size_t)m * HID + n] = acc[mf][nl][rr] + bias[n];
      }
    }
#undef TILE
#undef STG_A
#undef STG_B
}

// ---------------------------------------------------------------------------
// Flash attention, KVBLK=128: pair-scheduled 256 blocks x 512 threads.
// Per KV-tile (128 kv): stage K(dbuf 32K)+V(32K); one QK pass (8 t-frags,
// 64 MFMA/wave); one softmax pass; PV in two 64-kv halves through the
// 36KB P buffer (wave-private, lgkm-fenced). 3-barrier skeleton kept.
// Barrier/drain events per kv element HALVED vs KVBLK=64.
// LDS: K 64K + V 32K + P 36K = 132 KiB.
// vmcnt ladder: 12 outstanding -> vmcnt(8) K-landed; vmcnt(4) V-landed.
// ---------------------------------------------------------------------------
__global__ __launch_bounds__(512, 2)
void attn(const unsigned short* __restrict__ Qs,
          const unsigned short* __restrict__ Ks,
          const unsigned short* __restrict__ Vt,
          unsigned short* __restrict__ ctx)
{
  __shared__ alignas(16) unsigned short Klds[2][128 * 128];  // 2 x 32 KiB
  __shared__ alignas(16) unsigned short Vlds[128 * 128];     // 32 KiB (d-major)
  __shared__ alignas(16) unsigned short Plds[256 * 72];      // 36 KiB
  const int tid = threadIdx.x;
  const int w = tid >> 6, lane = tid & 63, g = lane >> 4, c = lane & 15;
  const int bid = blockIdx.x;
  const int head = bid & 31;
  const int j = bid >> 5;                 // 0..7
  const int qbh = 15 - j;
  const int q0w = (w < 4) ? ((qbh << 7) + w * 32) : ((j << 7) + (w - 4) * 32);
  const size_t plane = (size_t)head * (SEQ * HDIM);
  const unsigned short* Qp = Qs + plane;

  bf16x8 qf[2][4];
#pragma unroll
  for (int q2 = 0; q2 < 2; ++q2) {
    int s = q0w + q2 * 16 + c;
    int swb = (s & 7) << 3;
#pragma unroll
    for (int kk = 0; kk < 4; ++kk) {
      int d0 = kk * 32 + g * 8;
      qf[q2][kk] = *(const bf16x8*)(Qp + (size_t)s * HDIM + (d0 ^ swb));
    }
  }

  f32x4 accO[2][8];
#pragma unroll
  for (int i = 0; i < 2; ++i)
#pragma unroll
    for (int jj = 0; jj < 8; ++jj) {
      accO[i][jj][0] = 0.f; accO[i][jj][1] = 0.f; accO[i][jj][2] = 0.f; accO[i][jj][3] = 0.f;
    }
  float mrun[2] = { -1e30f, -1e30f };
  float lrun[2] = { 0.f, 0.f };

  const char* Kg = (const char*)(Ks + plane) + (tid >> 4) * 256 + (tid & 15) * 16;
  const char* Vg = (const char*)(Vt + plane) + (size_t)(tid >> 4) * 4096 + (tid & 15) * 16;

  const int ntiles = 16 - j;              // heavy qb needs (qbh+1)*128 kv
  const int qminw = q0w;
  const int qmaxw = q0w + 31;

  // K tile T = 32KB at Kg + T*32768; V tile T = column slice Vg + T*256.
#define STG_K(T, BUF) do { char* _kd = (char*)Klds[BUF] + tid * 16;            \
    const char* _kg = Kg + (size_t)(T) * 32768;                                \
    gl_lds16(_kg, _kd);              gl_lds16(_kg + 8192,  _kd + 8192);        \
    gl_lds16(_kg + 16384, _kd + 16384); gl_lds16(_kg + 24576, _kd + 24576); } while (0)
#define STG_V(T) do { char* _vd = (char*)Vlds + tid * 16;                      \
    const char* _vg = Vg + (T) * 256;                                          \
    gl_lds16(_vg, _vd);                gl_lds16(_vg + 131072, _vd + 8192);     \
    gl_lds16(_vg + 262144, _vd + 16384); gl_lds16(_vg + 393216, _vd + 24576); } while (0)

  STG_K(0, 0);

  for (int kt = 0; kt < ntiles; ++kt) {
    const int t0 = kt << 7;
    const bool havenext = (kt + 1 < ntiles);

    STG_V(kt);
    if (havenext) STG_K(kt + 1, (kt + 1) & 1);
    // K(kt) landed; V(kt)+K(kt+1) (8 ops) stay in flight
    if (havenext) asm volatile("s_waitcnt vmcnt(8)" ::: "memory");
    else          asm volatile("s_waitcnt vmcnt(4)" ::: "memory");
    __builtin_amdgcn_s_barrier();

    if (t0 <= qmaxw) {
      const char* Kb = (const char*)Klds[kt & 1];
      f32x4 sacc[8][2];
#pragma unroll
      for (int i = 0; i < 8; ++i)
#pragma unroll
        for (int jj = 0; jj < 2; ++jj) {
          sacc[i][jj][0] = 0.f; sacc[i][jj][1] = 0.f; sacc[i][jj][2] = 0.f; sacc[i][jj][3] = 0.f;
        }
      __builtin_amdgcn_s_setprio(1);
#pragma unroll
      for (int kk = 0; kk < 4; ++kk) {
        bf16x8 kf[8];
#pragma unroll
        for (int ta = 0; ta < 8; ++ta) {
          int t = ta * 16 + c;
          int d0 = kk * 32 + g * 8;
          kf[ta] = *(const bf16x8*)(Kb + t * 256 + ((d0 ^ ((t & 7) << 3)) << 1));
        }
#pragma unroll
        for (int ta = 0; ta < 8; ++ta)
#pragma unroll
          for (int q2 = 0; q2 < 2; ++q2)
            sacc[ta][q2] = mfma16(kf[ta], qf[q2][kk], sacc[ta][q2]);
      }
      __builtin_amdgcn_s_setprio(0);

      // causal mask (last tile of this wave's causal range always straddles)
      if (t0 + 127 > qminw) {
#pragma unroll
        for (int ta = 0; ta < 8; ++ta)
#pragma unroll
          for (int q2 = 0; q2 < 2; ++q2)
#pragma unroll
            for (int r = 0; r < 4; ++r) {
              int t = t0 + ta * 16 + g * 4 + r;
              int q = qminw + q2 * 16 + c;
              if (t > q) sacc[ta][q2][r] = -30000.f;
            }
      }

      float corr[2];
      bool resc = false;
#pragma unroll
      for (int q2 = 0; q2 < 2; ++q2) {
        float mx = -30000.f;
#pragma unroll
        for (int ta = 0; ta < 8; ++ta)
          mx = fmaxf(mx, fmaxf(fmaxf(sacc[ta][q2][0], sacc[ta][q2][1]),
                               fmaxf(sacc[ta][q2][2], sacc[ta][q2][3])));
        mx = fmaxf(mx, __shfl_xor(mx, 16));
        mx = fmaxf(mx, __shfl_xor(mx, 32));
        bool rs = mx > mrun[q2] + 8.0f;   // T13 defer-max
        resc |= rs;
        float mnew = rs ? mx : mrun[q2];
        corr[q2] = fexp2(mrun[q2] - mnew);
        mrun[q2] = mnew;
        float ls = 0.f;
#pragma unroll
        for (int ta = 0; ta < 8; ++ta)
#pragma unroll
          for (int r = 0; r < 4; ++r) {
            float e = fexp2(sacc[ta][q2][r] - mnew);
            sacc[ta][q2][r] = e;
            ls += e;
          }
        ls += __shfl_xor(ls, 16);
        ls += __shfl_xor(ls, 32);
        lrun[q2] = lrun[q2] * corr[q2] + ls;
      }

      if (__any(resc)) {
#pragma unroll
        for (int q2 = 0; q2 < 2; ++q2)
#pragma unroll
          for (int r = 0; r < 4; ++r) {
            float cD = __shfl(corr[q2], (lane & 48) | (((lane >> 4) << 2) + r));
#pragma unroll
            for (int fn = 0; fn < 8; ++fn) accO[q2][fn][r] *= cD;
          }
      }

      // wait for V before the PV halves (K(kt+1) may still fly)
      if (havenext) asm volatile("s_waitcnt vmcnt(4)" ::: "memory");
      else          asm volatile("s_waitcnt vmcnt(0)" ::: "memory");
      __builtin_amdgcn_s_barrier();

      // PV in two 64-kv halves through the wave-private P buffer
#pragma unroll
      for (int h = 0; h < 2; ++h) {
#pragma unroll
        for (int q2 = 0; q2 < 2; ++q2) {
          int prow = w * 32 + q2 * 16 + c;
#pragma unroll
          for (int t4 = 0; t4 < 4; ++t4) {
            u16x4 pk;
            pk[0] = f2bf(sacc[h * 4 + t4][q2][0]); pk[1] = f2bf(sacc[h * 4 + t4][q2][1]);
            pk[2] = f2bf(sacc[h * 4 + t4][q2][2]); pk[3] = f2bf(sacc[h * 4 + t4][q2][3]);
            *(u16x4*)(&Plds[prow * 72 + t4 * 16 + g * 4]) = pk;
          }
        }
        asm volatile("s_waitcnt lgkmcnt(0)" ::: "memory");
        __builtin_amdgcn_sched_barrier(0);
        __builtin_amdgcn_s_setprio(1);
#pragma unroll
        for (int kk = 0; kk < 2; ++kk) {
          bf16x8 pa[2];
#pragma unroll
          for (int q2 = 0; q2 < 2; ++q2)
            pa[q2] = *(const bf16x8*)((const char*)Plds + (w * 32 + q2 * 16 + c) * 144 + (kk * 32 + g * 8) * 2);
#pragma unroll
          for (int fn = 0; fn < 8; ++fn) {
            int d = fn * 16 + c;
            int tt = h * 64 + kk * 32 + g * 8;
            bf16x8 vb = *(const bf16x8*)((const char*)Vlds + d * 256 + ((tt ^ ((d & 7) << 3)) << 1));
#pragma unroll
            for (int q2 = 0; q2 < 2; ++q2)
              accO[q2][fn] = mfma16(pa[q2], vb, accO[q2][fn]);
          }
        }
        __builtin_amdgcn_s_setprio(0);
      }
    } else {
      // idle waves still participate in the block's barriers
      if (havenext) asm volatile("s_waitcnt vmcnt(4)" ::: "memory");
      else          asm volatile("s_waitcnt vmcnt(0)" ::: "memory");
      __builtin_amdgcn_s_barrier();
    }
    __builtin_amdgcn_s_barrier();   // all LDS reads done before next stage
  }
#undef STG_K
#undef STG_V

  const int b = head >> 4, nh = head & 15;
  float linv[2] = { 1.0f / lrun[0], 1.0f / lrun[1] };
#pragma unroll
  for (int q2 = 0; q2 < 2; ++q2)
#pragma unroll
    for (int r = 0; r < 4; ++r) {
      float inv = __shfl(linv[q2], (lane & 48) | (((lane >> 4) << 2) + r));
      int q = q0w + q2 * 16 + g * 4 + r;
      int m = q * 2 + b;
      int swb = ((m >> 1) & 7) << 3;
#pragma unroll
      for (int fn = 0; fn < 8; ++fn) {
        int h = nh * 128 + fn * 16 + c;
        ctx[(size_t)m * HID + (h ^ swb)] = f2bf(accO[q2][fn][r] * inv);
      }
    }
}

extern "C" void kernel_launch(void* const* d_in, const int* in_sizes, int n_in,
                              void* d_out, int out_size, void* d_ws, size_t ws_size,
                              hipStream_t stream) {
  const float* hidden = (const float*)d_in[0];
  const float* Wqkv = (const float*)d_in[2];
  const float* bqkv = (const float*)d_in[3];
  const float* Wd   = (const float*)d_in[4];
  const float* bd   = (const float*)d_in[5];
  float* out = (float*)d_out;
  char* ws = (char*)d_ws;

  const size_t OFF_HID  = 0;
  const size_t OFF_WQKV = 16777216;
  const size_t OFF_WD   = 41943040;
  const size_t OFF_COS  = 50331648;
  const size_t OFF_SIN  = 50855936;
  const size_t OFF_Q    = 51380224;
  const size_t OFF_K    = 68157440;
  const size_t OFF_VT   = 84934656;
  if (ws_size < 101711872) return;

  unsigned short* hidb  = (unsigned short*)(ws + OFF_HID);
  unsigned short* wqkvb = (unsigned short*)(ws + OFF_WQKV);
  unsigned short* wdb   = (unsigned short*)(ws + OFF_WD);
  float* cosT = (float*)(ws + OFF_COS);
  float* sinT = (float*)(ws + OFF_SIN);
  unsigned short* Qsb = (unsigned short*)(ws + OFF_Q);
  unsigned short* Ksb = (unsigned short*)(ws + OFF_K);
  unsigned short* Vtb = (unsigned short*)(ws + OFF_VT);
  unsigned short* ctxb = hidb;

  prep<<<25088, 256, 0, stream>>>(hidden, Wqkv, Wd, hidb, wqkvb, wdb, cosT, sinT);

  gemm_qkv<<<512, 512, 0, stream>>>(hidb, wqkvb, bqkv, Qsb, Ksb, Vtb, cosT, sinT);
  attn<<<256, 512, 0, stream>>>(Qsb, Ksb, Vtb, ctxb);
  gemm_out<<<256, 512, 0, stream>>>(ctxb, wdb, bd, out);
}